// Round 11
// baseline (243.967 us; speedup 1.0000x reference)
//
#include <hip/hip_runtime.h>
#include <hip/hip_bf16.h>
#include <stdint.h>

// MultiHeadedAttention: B=2, D_MODEL=1024, N=2048, H=16, HD=64.
// fp32 I/O, bf16 internal. Round 11: packed bf16 conversion
// (__float22bfloat162_rn -> v_cvt_pk_bf16_f32) in attn's hot loop and all
// epilogues; lsum kept as f32x4 (packed adds). Structure unchanged from R10.
#define DM 1024
#define NS 2048
#define NH 16
#define HD 64

typedef unsigned short u16;
typedef __attribute__((ext_vector_type(8))) short short8;
typedef __attribute__((ext_vector_type(4))) short s16x4;
typedef __attribute__((ext_vector_type(8))) unsigned short u16x8;
typedef __attribute__((ext_vector_type(4))) float f32x4;
typedef __attribute__((ext_vector_type(4))) unsigned short u16x4;

// gfx90a+ legacy-shape MFMA, present on gfx950 (ISA §10: v_mfma_f32_16x16x16_bf16)
#define MFMA_PV(a, b, c) __builtin_amdgcn_mfma_f32_16x16x16bf16_1k(a, b, c, 0, 0, 0)

static __device__ __forceinline__ u16 f2bf(float f) {
  union { float f; uint32_t i; } x; x.f = f;
  return (u16)((x.i + 0x7fffu + ((x.i >> 16) & 1u)) >> 16);
}
// packed RNE fp32x2 -> bf16x2 (single v_cvt_pk_bf16_f32 where HW supports it)
static __device__ __forceinline__ uint32_t pkbf(float a, float b) {
  union { __hip_bfloat162 h; uint32_t u; } cv;
  cv.h = __float22bfloat162_rn(float2{a, b});
  return cv.u;
}
static __device__ __forceinline__ u16x4 pkbf4(float a, float b, float c, float d) {
  union { uint32_t u[2]; u16x4 v; } cv;
  cv.u[0] = pkbf(a, b); cv.u[1] = pkbf(c, d);
  return cv.v;
}
static __device__ __forceinline__ s16x4 pkbf4s(float a, float b, float c, float d) {
  union { uint32_t u[2]; s16x4 v; } cv;
  cv.u[0] = pkbf(a, b); cv.u[1] = pkbf(c, d);
  return cv.v;
}
// async global->LDS, 16B/lane; LDS side wave-uniform base + lane*16 at all sites.
static __device__ __forceinline__ void gload16(u16* lds, const u16* g) {
  auto l = (__attribute__((address_space(3))) uint32_t*)(uint32_t)(uintptr_t)lds;
  auto gp = (const __attribute__((address_space(1))) uint32_t*)(uintptr_t)g;
  __builtin_amdgcn_global_load_lds(gp, l, 16, 0, 0);
}

// -------- fused weight convert: 4x fp32[DM*DM] -> bf16 --------
__global__ __launch_bounds__(256) void cvt4_k(const float* __restrict__ a,
                                              const float* __restrict__ b,
                                              const float* __restrict__ c,
                                              const float* __restrict__ d,
                                              u16* __restrict__ oa, u16* __restrict__ ob,
                                              u16* __restrict__ oc, u16* __restrict__ od) {
  const int y = blockIdx.y;
  const float* in = y == 0 ? a : y == 1 ? b : y == 2 ? c : d;
  u16* out = y == 0 ? oa : y == 1 ? ob : y == 2 ? oc : od;
  int i = (blockIdx.x * 256 + threadIdx.x) * 4;
  f32x4 v = *(const f32x4*)(in + i);
  *(u16x4*)(out + i) = pkbf4(v.x, v.y, v.z, v.w);
}

// -------- fused input transpose+downcast: fp32 [DM][NS] -> bf16 [NS][DM] -----
__global__ __launch_bounds__(256) void trf3_k(const float* __restrict__ q,
                                              const float* __restrict__ k,
                                              const float* __restrict__ v,
                                              u16* __restrict__ oq, u16* __restrict__ ok,
                                              u16* __restrict__ ov) {
  __shared__ __attribute__((aligned(16))) u16 t[64][65];
  const int z = blockIdx.z, b = z & 1, which = z >> 1;
  const float* in = which == 0 ? q : which == 1 ? k : v;
  u16* out = which == 0 ? oq : which == 1 ? ok : ov;
  const float* ip = in + (size_t)b * DM * NS;
  u16* op = out + (size_t)b * DM * NS;
  const int r0 = blockIdx.y * 64, c0 = blockIdx.x * 64;
  const int tx = threadIdx.x, ty = threadIdx.y;  // 16x16
#pragma unroll
  for (int j = 0; j < 4; ++j) {
    int row = ty + j * 16;
    f32x4 vv = *(const f32x4*)(ip + (size_t)(r0 + row) * NS + c0 + tx * 4);
    u16x4 bb = pkbf4(vv.x, vv.y, vv.z, vv.w);
    t[row][tx * 4 + 0] = bb.x; t[row][tx * 4 + 1] = bb.y;
    t[row][tx * 4 + 2] = bb.z; t[row][tx * 4 + 3] = bb.w;
  }
  __syncthreads();
#pragma unroll
  for (int j = 0; j < 4; ++j) {
    int crow = ty + j * 16;
    u16x4 vv;
    vv.x = t[tx * 4 + 0][crow]; vv.y = t[tx * 4 + 1][crow];
    vv.z = t[tx * 4 + 2][crow]; vv.w = t[tx * 4 + 3][crow];
    *(u16x4*)(op + (size_t)(c0 + crow) * DM + r0 + tx * 4) = vv;
  }
}

// -------- bf16 transpose [DM][NS] -> [NS][DM] per batch (for attn out) -------
__global__ __launch_bounds__(256) void tr_k(const u16* __restrict__ in,
                                            u16* __restrict__ out) {
  __shared__ __attribute__((aligned(16))) u16 t[64][65];
  const int b = blockIdx.z;
  const u16* ip = in + (size_t)b * DM * NS;
  u16* op = out + (size_t)b * DM * NS;
  const int r0 = blockIdx.y * 64, c0 = blockIdx.x * 64;
  const int tx = threadIdx.x, ty = threadIdx.y;
#pragma unroll
  for (int j = 0; j < 4; ++j) {
    int row = ty + j * 16;
    u16x4 v = *(const u16x4*)(ip + (size_t)(r0 + row) * NS + c0 + tx * 4);
    t[row][tx * 4 + 0] = v.x; t[row][tx * 4 + 1] = v.y;
    t[row][tx * 4 + 2] = v.z; t[row][tx * 4 + 3] = v.w;
  }
  __syncthreads();
#pragma unroll
  for (int j = 0; j < 4; ++j) {
    int crow = ty + j * 16;
    u16x4 v;
    v.x = t[tx * 4 + 0][crow]; v.y = t[tx * 4 + 1][crow];
    v.z = t[tx * 4 + 2][crow]; v.w = t[tx * 4 + 3][crow];
    *(u16x4*)(op + (size_t)(c0 + crow) * DM + r0 + tx * 4) = v;
  }
}

// ---------------- fused QKV projection GEMM ----------------
// grid (NS/128, DM/128, 6); z = which*2 + b.  128x128 tile, BK=32, swizzled LDS.
// Q output is pre-scaled by SC = 0.125*log2(e) (folded softmax scale).
__global__ __launch_bounds__(256) void qkv_k(
    const u16* __restrict__ Xq, const u16* __restrict__ Xk, const u16* __restrict__ Xv,
    const u16* __restrict__ Wq, const u16* __restrict__ Wk, const u16* __restrict__ Wv,
    const float* __restrict__ bq, const float* __restrict__ bk, const float* __restrict__ bv,
    u16* __restrict__ QH, u16* __restrict__ KH, u16* __restrict__ VH) {
  __shared__ __attribute__((aligned(16))) u16 As[128 * 32];
  __shared__ __attribute__((aligned(16))) u16 Bs[128 * 32];
  const int z = blockIdx.z, b = z & 1, which = z >> 1;
  const u16* X = which == 0 ? Xq : which == 1 ? Xk : Xv;
  const u16* W = which == 0 ? Wq : which == 1 ? Wk : Wv;
  const float* bias = which == 0 ? bq : which == 1 ? bk : bv;
  u16* out = which == 0 ? QH : which == 1 ? KH : VH;
  const float sc = which == 0 ? 0.18033688011112042f : 1.0f;  // 0.125*log2e
  const int m0 = blockIdx.x * 128;
  const int c0 = blockIdx.y * 128;
  const u16* Xb = X + (size_t)b * NS * DM;
  const int tid = threadIdx.x;
  const int lane = tid & 63, w = tid >> 6;
  const int wm = w >> 1, wc = w & 1;
  const int qd = lane >> 4, ml = lane & 15;
  const int sml = (ml >> 1) & 3;  // read-side swizzle key

  f32x4 acc[4][4];
#pragma unroll
  for (int i = 0; i < 4; ++i)
#pragma unroll
    for (int j = 0; j < 4; ++j) acc[i][j] = (f32x4){0.f, 0.f, 0.f, 0.f};

  for (int k0 = 0; k0 < DM; k0 += 32) {
    __syncthreads();
#pragma unroll
    for (int it = 0; it < 2; ++it) {
      int ci = it * 256 + tid;
      int row = ci >> 2;
      int jg = (ci & 3) ^ ((ci >> 3) & 3);  // chunk swizzle (row>>1)&3
      gload16(&As[ci * 8], Xb + (size_t)(m0 + row) * DM + k0 + jg * 8);
      gload16(&Bs[ci * 8], W + (size_t)(c0 + row) * DM + k0 + jg * 8);
    }
    __syncthreads();
    short8 af[4], bf[4];
#pragma unroll
    for (int i = 0; i < 4; ++i) {
      af[i] = *(const short8*)&As[(wm * 64 + i * 16 + ml) * 32 + ((qd ^ sml) * 8)];
      bf[i] = *(const short8*)&Bs[(wc * 64 + i * 16 + ml) * 32 + ((qd ^ sml) * 8)];
    }
#pragma unroll
    for (int mi = 0; mi < 4; ++mi)
#pragma unroll
      for (int ci2 = 0; ci2 < 4; ++ci2)
        acc[mi][ci2] = __builtin_amdgcn_mfma_f32_16x16x32_bf16(af[mi], bf[ci2],
                                                               acc[mi][ci2], 0, 0, 0);
  }

  const int cw = c0 + wc * 64;
  const int mw = m0 + wm * 64;
  float bv4[4];
#pragma unroll
  for (int ci2 = 0; ci2 < 4; ++ci2) bv4[ci2] = bias[cw + ci2 * 16 + ml];

  if (which < 2) {
    const int h = ml, d0 = cw >> 4;
    u16* ob = out + ((size_t)(b * NH + h) * NS) * HD;
#pragma unroll
    for (int mi = 0; mi < 4; ++mi) {
#pragma unroll
      for (int r = 0; r < 4; ++r) {
        int n = mw + mi * 16 + qd * 4 + r;
        *(u16x4*)(ob + (size_t)n * HD + d0) =
            pkbf4((acc[mi][0][r] + bv4[0]) * sc, (acc[mi][1][r] + bv4[1]) * sc,
                  (acc[mi][2][r] + bv4[2]) * sc, (acc[mi][3][r] + bv4[3]) * sc);
      }
    }
  } else {
#pragma unroll
    for (int ci2 = 0; ci2 < 4; ++ci2) {
      int c = cw + ci2 * 16 + ml;
      int h = c & 15, d = c >> 4;
#pragma unroll
      for (int mi = 0; mi < 4; ++mi) {
        int nb = mw + mi * 16 + qd * 4;
        *(u16x4*)(out + ((size_t)(b * NH + h) * HD + d) * NS + nb) =
            pkbf4(acc[mi][ci2][0] + bv4[ci2], acc[mi][ci2][1] + bv4[ci2],
                  acc[mi][ci2][2] + bv4[ci2], acc[mi][ci2][3] + bv4[ci2]);
      }
    }
  }
}

// ---------------- output projection, 64x128 tiles (fp32 out) ----------------
__global__ __launch_bounds__(256) void proj_o(const u16* __restrict__ X,
                                              const u16* __restrict__ W,
                                              const float* __restrict__ bias,
                                              float* __restrict__ out) {
  __shared__ __attribute__((aligned(16))) u16 As[64 * 32];
  __shared__ __attribute__((aligned(16))) u16 Bs[128 * 32];
  const int b = blockIdx.z;
  const int m0 = blockIdx.x * 64;
  const int c0 = blockIdx.y * 128;
  const u16* Xb = X + (size_t)b * NS * DM;
  const int tid = threadIdx.x;
  const int lane = tid & 63, w = tid >> 6;
  const int wm = w >> 1, wc = w & 1;  // wave tile: 32 rows x 64 cols
  const int qd = lane >> 4, ml = lane & 15;
  const int sml = (ml >> 1) & 3;

  f32x4 acc[2][4];
#pragma unroll
  for (int i = 0; i < 2; ++i)
#pragma unroll
    for (int j = 0; j < 4; ++j) acc[i][j] = (f32x4){0.f, 0.f, 0.f, 0.f};

  for (int k0 = 0; k0 < DM; k0 += 32) {
    __syncthreads();
    {  // A: 256 chunks (64 rows x 4), one per thread
      int jg = (tid & 3) ^ ((tid >> 3) & 3);
      int row = tid >> 2;
      gload16(&As[tid * 8], Xb + (size_t)(m0 + row) * DM + k0 + jg * 8);
    }
#pragma unroll
    for (int it = 0; it < 2; ++it) {  // B: 512 chunks (128 rows x 4)
      int ci = it * 256 + tid;
      int row = ci >> 2;
      int jg = (ci & 3) ^ ((ci >> 3) & 3);
      gload16(&Bs[ci * 8], W + (size_t)(c0 + row) * DM + k0 + jg * 8);
    }
    __syncthreads();
    short8 af[2], bf[4];
#pragma unroll
    for (int i = 0; i < 2; ++i)
      af[i] = *(const short8*)&As[(wm * 32 + i * 16 + ml) * 32 + ((qd ^ sml) * 8)];
#pragma unroll
    for (int i = 0; i < 4; ++i)
      bf[i] = *(const short8*)&Bs[(wc * 64 + i * 16 + ml) * 32 + ((qd ^ sml) * 8)];
#pragma unroll
    for (int mi = 0; mi < 2; ++mi)
#pragma unroll
      for (int ci2 = 0; ci2 < 4; ++ci2)
        acc[mi][ci2] = __builtin_amdgcn_mfma_f32_16x16x32_bf16(af[mi], bf[ci2],
                                                               acc[mi][ci2], 0, 0, 0);
  }

  const int cw = c0 + wc * 64;
  const int mw = m0 + wm * 32;
#pragma unroll
  for (int ci2 = 0; ci2 < 4; ++ci2) {
    int c = cw + ci2 * 16 + ml;
    float bv = bias[c];
#pragma unroll
    for (int mi = 0; mi < 2; ++mi) {
      int nb = mw + mi * 16 + qd * 4;
      f32x4 v;
      v.x = acc[mi][ci2][0] + bv; v.y = acc[mi][ci2][1] + bv;
      v.z = acc[mi][ci2][2] + bv; v.w = acc[mi][ci2][3] + bv;
      *(f32x4*)(out + ((size_t)b * DM + c) * NS + nb) = v;
    }
  }
}

// ---------------- flash attention, register-P, async dbuf, swizzled ----------
// Q,K: [bh][n][d] (Q pre-scaled by 0.125*log2e), V: [bh][d][n].
// grid (NS/64, 32). S^T = mfma(K,Q) keeps P in registers; PV via 16x16x16.
// K/V double-buffered via global_load_lds; ONE barrier per 64-key tile.
// Swizzle s(row)=(row>>1)&3 on 16B chunks: K b128 reads conflict-free, V b64
// reads 2-way (the floor for 16B placement granularity).
__global__ __launch_bounds__(256) void attn_k(const u16* __restrict__ Q,
                                              const u16* __restrict__ K,
                                              const u16* __restrict__ V,
                                              u16* __restrict__ XO) {
  __shared__ __attribute__((aligned(16))) u16 Ks[2 * 2 * 2048];  // [buf][slab][64][32]
  __shared__ __attribute__((aligned(16))) u16 Vs[2 * 2 * 2048];  // [buf][slab][64 d][32]
  const int bh = blockIdx.y, b = bh >> 4, h = bh & 15;
  const int n0 = blockIdx.x * 64;
  const u16* Qb = Q + (size_t)bh * NS * HD;
  const u16* Kb = K + (size_t)bh * NS * HD;
  const u16* Vb = V + (size_t)bh * HD * NS;
  const int tid = threadIdx.x, lane = tid & 63, w = tid >> 6;
  const int qd = lane >> 4, ml = lane & 15;
  const int sml = (ml >> 1) & 3;

  // Q fragments straight from global (each row read by exactly one block)
  short8 aq[2];
  {
    const u16* qr = Qb + (size_t)(n0 + w * 16 + ml) * HD + qd * 8;
    aq[0] = *(const short8*)qr;
    aq[1] = *(const short8*)(qr + 32);
  }

  const int srow = tid >> 2;                       // staging row (key or d)
  const int jg = (tid & 3) ^ ((tid >> 3) & 3);     // swizzled 16B chunk

  // prologue: tile 0 -> buf 0
#pragma unroll
  for (int s = 0; s < 2; ++s) {
    gload16(&Ks[s * 2048 + tid * 8], Kb + (size_t)srow * HD + s * 32 + jg * 8);
    gload16(&Vs[s * 2048 + tid * 8], Vb + (size_t)srow * NS + s * 32 + jg * 8);
  }
  __syncthreads();

  f32x4 O[4];
#pragma unroll
  for (int i = 0; i < 4; ++i) O[i] = (f32x4){0.f, 0.f, 0.f, 0.f};
  f32x4 lsum4 = (f32x4){0.f, 0.f, 0.f, 0.f};  // packed row-sum accumulator

  for (int kb = 0; kb < NS / 64; ++kb) {
    const int cur = kb & 1, nxt = cur ^ 1;
    if (kb < NS / 64 - 1) {  // prefetch tile kb+1 into the other buffer
#pragma unroll
      for (int s = 0; s < 2; ++s) {
        gload16(&Ks[(nxt * 2 + s) * 2048 + tid * 8],
                Kb + (size_t)((kb + 1) * 64 + srow) * HD + s * 32 + jg * 8);
        gload16(&Vs[(nxt * 2 + s) * 2048 + tid * 8],
                Vb + (size_t)srow * NS + (kb + 1) * 64 + s * 32 + jg * 8);
      }
    }

    // S^T = K Q^T  (D[key][qrow]; A=K frag, B=Q frag)
    const u16* kbase = &Ks[cur * 2 * 2048];
    f32x4 S[4];
#pragma unroll
    for (int f = 0; f < 4; ++f) S[f] = (f32x4){0.f, 0.f, 0.f, 0.f};
#pragma unroll
    for (int f = 0; f < 4; ++f)
#pragma unroll
      for (int ks = 0; ks < 2; ++ks) {
        short8 bk = *(const short8*)&kbase[ks * 2048 + (f * 16 + ml) * 32 +
                                           ((qd ^ sml) * 8)];
        S[f] = __builtin_amdgcn_mfma_f32_16x16x32_bf16(bk, aq[ks], S[f], 0, 0, 0);
      }

    // P = exp2(S^T) in registers; packed cvt to 16x16x16 A-frags
    s16x4 pf[4];
#pragma unroll
    for (int f = 0; f < 4; ++f) {
      f32x4 p;
      p.x = __builtin_amdgcn_exp2f(S[f][0]);
      p.y = __builtin_amdgcn_exp2f(S[f][1]);
      p.z = __builtin_amdgcn_exp2f(S[f][2]);
      p.w = __builtin_amdgcn_exp2f(S[f][3]);
      lsum4 += p;
      pf[f] = pkbf4s(p.x, p.y, p.z, p.w);
    }

    // O += P V  (16 keys per step; B-frag = V[d][key] b64 reads, de-swizzled)
    const u16* vbase = &Vs[cur * 2 * 2048];
#pragma unroll
    for (int t = 0; t < 4; ++t) {
      const int vs = t >> 1;
      const int voff = ((((t & 1) * 2 + (qd >> 1)) ^ sml) * 8) + (qd & 1) * 4;
#pragma unroll
      for (int df = 0; df < 4; ++df) {
        s16x4 vb = *(const s16x4*)&vbase[vs * 2048 + (df * 16 + ml) * 32 + voff];
        O[df] = MFMA_PV(pf[t], vb, O[df]);
      }
    }
    __syncthreads();  // readers of cur done + prefetch into nxt drained
  }

  // reduce lsum over the 4 quads holding the same qrow=ml
  float lsum = (lsum4.x + lsum4.y) + (lsum4.z + lsum4.w);
  lsum += __shfl_xor(lsum, 16);
  lsum += __shfl_xor(lsum, 32);
  float linv[4];
#pragma unroll
  for (int r = 0; r < 4; ++r) linv[r] = 1.f / __shfl(lsum, qd * 4 + r);

  const int nb = n0 + w * 16 + qd * 4;
#pragma unroll
  for (int df = 0; df < 4; ++df) {
    int d = df * 16 + ml;
    int c = d * NH + h;  // reshape: c = d*H + h
    *(u16x4*)(XO + ((size_t)b * DM + c) * NS + nb) =
        pkbf4(O[df][0] * linv[0], O[df][1] * linv[1],
              O[df][2] * linv[2], O[df][3] * linv[3]);
  }
}

extern "C" void kernel_launch(void* const* d_in, const int* in_sizes, int n_in,
                              void* d_out, int out_size, void* d_ws, size_t ws_size,
                              hipStream_t stream) {
  const float* query = (const float*)d_in[0];
  const float* key = (const float*)d_in[1];
  const float* value = (const float*)d_in[2];
  const float* Wq = (const float*)d_in[3]; const float* bq = (const float*)d_in[4];
  const float* Wk = (const float*)d_in[5]; const float* bk = (const float*)d_in[6];
  const float* Wv = (const float*)d_in[7]; const float* bv = (const float*)d_in[8];
  const float* Wm = (const float*)d_in[9]; const float* bm = (const float*)d_in[10];

  u16* ws = (u16*)d_ws;
  const size_t TS = (size_t)2 * NS * DM;   // 4,194,304 u16 elems
  const size_t WSZ = (size_t)DM * DM;
  u16* XTq = ws;
  u16* XTk = ws + TS;
  u16* XTv = ws + 2 * TS;
  u16* QH = ws + 3 * TS;
  u16* KH = ws + 4 * TS;
  u16* VH = ws + 5 * TS;
  u16* Wqb = ws + 6 * TS;
  u16* Wkb = Wqb + WSZ;
  u16* Wvb = Wkb + WSZ;
  u16* Wmb = Wvb + WSZ;
  u16* XO = XTq;   // XTq fully consumed by qkv_k before attn writes
  u16* XOT = XTk;  // XTk fully consumed before the XO transpose

  cvt4_k<<<dim3(WSZ / 1024, 4), 256, 0, stream>>>(Wq, Wk, Wv, Wm, Wqb, Wkb, Wvb, Wmb);

  dim3 tb(16, 16);
  trf3_k<<<dim3(NS / 64, DM / 64, 6), tb, 0, stream>>>(query, key, value, XTq, XTk, XTv);

  qkv_k<<<dim3(NS / 128, DM / 128, 6), 256, 0, stream>>>(
      XTq, XTk, XTv, Wqb, Wkb, Wvb, bq, bk, bv, QH, KH, VH);

  attn_k<<<dim3(NS / 64, 32), 256, 0, stream>>>(QH, KH, VH, XO);

  tr_k<<<dim3(NS / 64, DM / 64, 2), tb, 0, stream>>>(XO, XOT);
  proj_o<<<dim3(NS / 64, DM / 128, 2), 256, 0, stream>>>(XOT, Wmb, bm, (float*)d_out);
}

// Round 12
// 237.289 us; speedup vs baseline: 1.0281x; 1.0281x over previous
//
#include <hip/hip_runtime.h>
#include <hip/hip_bf16.h>
#include <stdint.h>

// MultiHeadedAttention: B=2, D_MODEL=1024, N=2048, H=16, HD=64.
// fp32 I/O, bf16 internal. Round 12: tr_k deleted. attn PV operands swapped
// (A/B layouts of 16x16x16 are lane-identical) -> O^T in registers -> attn
// writes [b][n][h*64+d] coalesced; Wm columns permuted once (cvtp_k) so
// proj_o's contraction index matches. One fewer kernel + 33 MB less HBM.
#define DM 1024
#define NS 2048
#define NH 16
#define HD 64

typedef unsigned short u16;
typedef __attribute__((ext_vector_type(8))) short short8;
typedef __attribute__((ext_vector_type(4))) short s16x4;
typedef __attribute__((ext_vector_type(8))) unsigned short u16x8;
typedef __attribute__((ext_vector_type(4))) float f32x4;
typedef __attribute__((ext_vector_type(4))) unsigned short u16x4;

// gfx90a+ legacy-shape MFMA, present on gfx950 (ISA §10: v_mfma_f32_16x16x16_bf16)
#define MFMA_PV(a, b, c) __builtin_amdgcn_mfma_f32_16x16x16bf16_1k(a, b, c, 0, 0, 0)

// packed RNE fp32x2 -> bf16x2 (v_cvt_pk_bf16_f32 where HW supports it)
static __device__ __forceinline__ uint32_t pkbf(float a, float b) {
  union { __hip_bfloat162 h; uint32_t u; } cv;
  cv.h = __float22bfloat162_rn(float2{a, b});
  return cv.u;
}
static __device__ __forceinline__ u16x4 pkbf4(float a, float b, float c, float d) {
  union { uint32_t u[2]; u16x4 v; } cv;
  cv.u[0] = pkbf(a, b); cv.u[1] = pkbf(c, d);
  return cv.v;
}
static __device__ __forceinline__ s16x4 pkbf4s(float a, float b, float c, float d) {
  union { uint32_t u[2]; s16x4 v; } cv;
  cv.u[0] = pkbf(a, b); cv.u[1] = pkbf(c, d);
  return cv.v;
}
// async global->LDS, 16B/lane; LDS side wave-uniform base + lane*16 at all sites.
static __device__ __forceinline__ void gload16(u16* lds, const u16* g) {
  auto l = (__attribute__((address_space(3))) uint32_t*)(uint32_t)(uintptr_t)lds;
  auto gp = (const __attribute__((address_space(1))) uint32_t*)(uintptr_t)g;
  __builtin_amdgcn_global_load_lds(gp, l, 16, 0, 0);
}

// -------- weight convert: 3x fp32[DM*DM] -> bf16 (Wq, Wk, Wv) --------
__global__ __launch_bounds__(256) void cvt3_k(const float* __restrict__ a,
                                              const float* __restrict__ b,
                                              const float* __restrict__ c,
                                              u16* __restrict__ oa, u16* __restrict__ ob,
                                              u16* __restrict__ oc) {
  const int y = blockIdx.y;
  const float* in = y == 0 ? a : y == 1 ? b : c;
  u16* out = y == 0 ? oa : y == 1 ? ob : oc;
  int i = (blockIdx.x * 256 + threadIdx.x) * 4;
  f32x4 v = *(const f32x4*)(in + i);
  *(u16x4*)(out + i) = pkbf4(v.x, v.y, v.z, v.w);
}

// -------- Wm convert + column permute: out[c][h*64+d] = bf16(in[c][d*16+h]) --
// Per c-row: 64x16 transpose through LDS. 4 rows per 256-thread block.
__global__ __launch_bounds__(256) void cvtp_k(const float* __restrict__ in,
                                              u16* __restrict__ out) {
  __shared__ __attribute__((aligned(16))) u16 t[4][16][68];  // [row][h][d]
  const int tid = threadIdx.x;
  const int rr = tid >> 6, tl = tid & 63;
  const int row = blockIdx.x * 4 + rr;
  const float* ip = in + (size_t)row * DM;
  u16* op = out + (size_t)row * DM;
#pragma unroll
  for (int e = 0; e < 4; ++e) {
    int i = e * 256 + tl * 4;          // coalesced f32x4; h0 = i&15 in {0,4,8,12}
    f32x4 v = *(const f32x4*)(ip + i);
    u16x4 bb = pkbf4(v.x, v.y, v.z, v.w);
    int d = i >> 4, h0 = i & 15;
    t[rr][h0 + 0][d] = bb.x; t[rr][h0 + 1][d] = bb.y;
    t[rr][h0 + 2][d] = bb.z; t[rr][h0 + 3][d] = bb.w;
  }
  __syncthreads();
#pragma unroll
  for (int e = 0; e < 4; ++e) {
    int j = e * 256 + tl * 4;          // out index j = h*64+d, coalesced
    int h = j >> 6, d = j & 63;
    u16x4 v;
    v.x = t[rr][h][d + 0]; v.y = t[rr][h][d + 1];
    v.z = t[rr][h][d + 2]; v.w = t[rr][h][d + 3];
    *(u16x4*)(op + j) = v;
  }
}

// -------- fused input transpose+downcast: fp32 [DM][NS] -> bf16 [NS][DM] -----
__global__ __launch_bounds__(256) void trf3_k(const float* __restrict__ q,
                                              const float* __restrict__ k,
                                              const float* __restrict__ v,
                                              u16* __restrict__ oq, u16* __restrict__ ok,
                                              u16* __restrict__ ov) {
  __shared__ __attribute__((aligned(16))) u16 t[64][65];
  const int z = blockIdx.z, b = z & 1, which = z >> 1;
  const float* in = which == 0 ? q : which == 1 ? k : v;
  u16* out = which == 0 ? oq : which == 1 ? ok : ov;
  const float* ip = in + (size_t)b * DM * NS;
  u16* op = out + (size_t)b * DM * NS;
  const int r0 = blockIdx.y * 64, c0 = blockIdx.x * 64;
  const int tx = threadIdx.x, ty = threadIdx.y;  // 16x16
#pragma unroll
  for (int j = 0; j < 4; ++j) {
    int row = ty + j * 16;
    f32x4 vv = *(const f32x4*)(ip + (size_t)(r0 + row) * NS + c0 + tx * 4);
    u16x4 bb = pkbf4(vv.x, vv.y, vv.z, vv.w);
    t[row][tx * 4 + 0] = bb.x; t[row][tx * 4 + 1] = bb.y;
    t[row][tx * 4 + 2] = bb.z; t[row][tx * 4 + 3] = bb.w;
  }
  __syncthreads();
#pragma unroll
  for (int j = 0; j < 4; ++j) {
    int crow = ty + j * 16;
    u16x4 vv;
    vv.x = t[tx * 4 + 0][crow]; vv.y = t[tx * 4 + 1][crow];
    vv.z = t[tx * 4 + 2][crow]; vv.w = t[tx * 4 + 3][crow];
    *(u16x4*)(op + (size_t)(c0 + crow) * DM + r0 + tx * 4) = vv;
  }
}

// ---------------- fused QKV projection GEMM ----------------
// grid (NS/128, DM/128, 6); z = which*2 + b.  128x128 tile, BK=32, swizzled LDS.
// Q output is pre-scaled by SC = 0.125*log2(e) (folded softmax scale).
__global__ __launch_bounds__(256) void qkv_k(
    const u16* __restrict__ Xq, const u16* __restrict__ Xk, const u16* __restrict__ Xv,
    const u16* __restrict__ Wq, const u16* __restrict__ Wk, const u16* __restrict__ Wv,
    const float* __restrict__ bq, const float* __restrict__ bk, const float* __restrict__ bv,
    u16* __restrict__ QH, u16* __restrict__ KH, u16* __restrict__ VH) {
  __shared__ __attribute__((aligned(16))) u16 As[128 * 32];
  __shared__ __attribute__((aligned(16))) u16 Bs[128 * 32];
  const int z = blockIdx.z, b = z & 1, which = z >> 1;
  const u16* X = which == 0 ? Xq : which == 1 ? Xk : Xv;
  const u16* W = which == 0 ? Wq : which == 1 ? Wk : Wv;
  const float* bias = which == 0 ? bq : which == 1 ? bk : bv;
  u16* out = which == 0 ? QH : which == 1 ? KH : VH;
  const float sc = which == 0 ? 0.18033688011112042f : 1.0f;  // 0.125*log2e
  const int m0 = blockIdx.x * 128;
  const int c0 = blockIdx.y * 128;
  const u16* Xb = X + (size_t)b * NS * DM;
  const int tid = threadIdx.x;
  const int lane = tid & 63, w = tid >> 6;
  const int wm = w >> 1, wc = w & 1;
  const int qd = lane >> 4, ml = lane & 15;
  const int sml = (ml >> 1) & 3;  // read-side swizzle key

  f32x4 acc[4][4];
#pragma unroll
  for (int i = 0; i < 4; ++i)
#pragma unroll
    for (int j = 0; j < 4; ++j) acc[i][j] = (f32x4){0.f, 0.f, 0.f, 0.f};

  for (int k0 = 0; k0 < DM; k0 += 32) {
    __syncthreads();
#pragma unroll
    for (int it = 0; it < 2; ++it) {
      int ci = it * 256 + tid;
      int row = ci >> 2;
      int jg = (ci & 3) ^ ((ci >> 3) & 3);  // chunk swizzle (row>>1)&3
      gload16(&As[ci * 8], Xb + (size_t)(m0 + row) * DM + k0 + jg * 8);
      gload16(&Bs[ci * 8], W + (size_t)(c0 + row) * DM + k0 + jg * 8);
    }
    __syncthreads();
    short8 af[4], bf[4];
#pragma unroll
    for (int i = 0; i < 4; ++i) {
      af[i] = *(const short8*)&As[(wm * 64 + i * 16 + ml) * 32 + ((qd ^ sml) * 8)];
      bf[i] = *(const short8*)&Bs[(wc * 64 + i * 16 + ml) * 32 + ((qd ^ sml) * 8)];
    }
#pragma unroll
    for (int mi = 0; mi < 4; ++mi)
#pragma unroll
      for (int ci2 = 0; ci2 < 4; ++ci2)
        acc[mi][ci2] = __builtin_amdgcn_mfma_f32_16x16x32_bf16(af[mi], bf[ci2],
                                                               acc[mi][ci2], 0, 0, 0);
  }

  const int cw = c0 + wc * 64;
  const int mw = m0 + wm * 64;
  float bv4[4];
#pragma unroll
  for (int ci2 = 0; ci2 < 4; ++ci2) bv4[ci2] = bias[cw + ci2 * 16 + ml];

  if (which < 2) {
    const int h = ml, d0 = cw >> 4;
    u16* ob = out + ((size_t)(b * NH + h) * NS) * HD;
#pragma unroll
    for (int mi = 0; mi < 4; ++mi) {
#pragma unroll
      for (int r = 0; r < 4; ++r) {
        int n = mw + mi * 16 + qd * 4 + r;
        *(u16x4*)(ob + (size_t)n * HD + d0) =
            pkbf4((acc[mi][0][r] + bv4[0]) * sc, (acc[mi][1][r] + bv4[1]) * sc,
                  (acc[mi][2][r] + bv4[2]) * sc, (acc[mi][3][r] + bv4[3]) * sc);
      }
    }
  } else {
#pragma unroll
    for (int ci2 = 0; ci2 < 4; ++ci2) {
      int c = cw + ci2 * 16 + ml;
      int h = c & 15, d = c >> 4;
#pragma unroll
      for (int mi = 0; mi < 4; ++mi) {
        int nb = mw + mi * 16 + qd * 4;
        *(u16x4*)(out + ((size_t)(b * NH + h) * HD + d) * NS + nb) =
            pkbf4(acc[mi][ci2][0] + bv4[ci2], acc[mi][ci2][1] + bv4[ci2],
                  acc[mi][ci2][2] + bv4[ci2], acc[mi][ci2][3] + bv4[ci2]);
      }
    }
  }
}

// ---------------- output projection, 64x128 tiles (fp32 out) ----------------
// X: [b][n][j] (j = h*64+d, attn output), W: Wm' with permuted columns.
__global__ __launch_bounds__(256) void proj_o(const u16* __restrict__ X,
                                              const u16* __restrict__ W,
                                              const float* __restrict__ bias,
                                              float* __restrict__ out) {
  __shared__ __attribute__((aligned(16))) u16 As[64 * 32];
  __shared__ __attribute__((aligned(16))) u16 Bs[128 * 32];
  const int b = blockIdx.z;
  const int m0 = blockIdx.x * 64;
  const int c0 = blockIdx.y * 128;
  const u16* Xb = X + (size_t)b * NS * DM;
  const int tid = threadIdx.x;
  const int lane = tid & 63, w = tid >> 6;
  const int wm = w >> 1, wc = w & 1;  // wave tile: 32 rows x 64 cols
  const int qd = lane >> 4, ml = lane & 15;
  const int sml = (ml >> 1) & 3;

  f32x4 acc[2][4];
#pragma unroll
  for (int i = 0; i < 2; ++i)
#pragma unroll
    for (int j = 0; j < 4; ++j) acc[i][j] = (f32x4){0.f, 0.f, 0.f, 0.f};

  for (int k0 = 0; k0 < DM; k0 += 32) {
    __syncthreads();
    {  // A: 256 chunks (64 rows x 4), one per thread
      int jg = (tid & 3) ^ ((tid >> 3) & 3);
      int row = tid >> 2;
      gload16(&As[tid * 8], Xb + (size_t)(m0 + row) * DM + k0 + jg * 8);
    }
#pragma unroll
    for (int it = 0; it < 2; ++it) {  // B: 512 chunks (128 rows x 4)
      int ci = it * 256 + tid;
      int row = ci >> 2;
      int jg = (ci & 3) ^ ((ci >> 3) & 3);
      gload16(&Bs[ci * 8], W + (size_t)(c0 + row) * DM + k0 + jg * 8);
    }
    __syncthreads();
    short8 af[2], bf[4];
#pragma unroll
    for (int i = 0; i < 2; ++i)
      af[i] = *(const short8*)&As[(wm * 32 + i * 16 + ml) * 32 + ((qd ^ sml) * 8)];
#pragma unroll
    for (int i = 0; i < 4; ++i)
      bf[i] = *(const short8*)&Bs[(wc * 64 + i * 16 + ml) * 32 + ((qd ^ sml) * 8)];
#pragma unroll
    for (int mi = 0; mi < 2; ++mi)
#pragma unroll
      for (int ci2 = 0; ci2 < 4; ++ci2)
        acc[mi][ci2] = __builtin_amdgcn_mfma_f32_16x16x32_bf16(af[mi], bf[ci2],
                                                               acc[mi][ci2], 0, 0, 0);
  }

  const int cw = c0 + wc * 64;
  const int mw = m0 + wm * 32;
#pragma unroll
  for (int ci2 = 0; ci2 < 4; ++ci2) {
    int c = cw + ci2 * 16 + ml;
    float bv = bias[c];
#pragma unroll
    for (int mi = 0; mi < 2; ++mi) {
      int nb = mw + mi * 16 + qd * 4;
      f32x4 v;
      v.x = acc[mi][ci2][0] + bv; v.y = acc[mi][ci2][1] + bv;
      v.z = acc[mi][ci2][2] + bv; v.w = acc[mi][ci2][3] + bv;
      *(f32x4*)(out + ((size_t)b * DM + c) * NS + nb) = v;
    }
  }
}

// ---------------- flash attention, register-P, async dbuf, swizzled ----------
// Q,K: [bh][n][d] (Q pre-scaled by 0.125*log2e), V: [bh][d][n].
// grid (NS/64, 32). S^T = mfma(K,Q) keeps P in registers; PV = mfma(V,P)
// (operands swapped -> O^T: row=d, col=qrow) so the epilogue writes
// [b][n][h*64+d] with contiguous u16x4 stores. ONE barrier per 64-key tile.
__global__ __launch_bounds__(256) void attn_k(const u16* __restrict__ Q,
                                              const u16* __restrict__ K,
                                              const u16* __restrict__ V,
                                              u16* __restrict__ XO) {
  __shared__ __attribute__((aligned(16))) u16 Ks[2 * 2 * 2048];  // [buf][slab][64][32]
  __shared__ __attribute__((aligned(16))) u16 Vs[2 * 2 * 2048];  // [buf][slab][64 d][32]
  const int bh = blockIdx.y, b = bh >> 4, h = bh & 15;
  const int n0 = blockIdx.x * 64;
  const u16* Qb = Q + (size_t)bh * NS * HD;
  const u16* Kb = K + (size_t)bh * NS * HD;
  const u16* Vb = V + (size_t)bh * HD * NS;
  const int tid = threadIdx.x, lane = tid & 63, w = tid >> 6;
  const int qd = lane >> 4, ml = lane & 15;
  const int sml = (ml >> 1) & 3;

  // Q fragments straight from global (each row read by exactly one block)
  short8 aq[2];
  {
    const u16* qr = Qb + (size_t)(n0 + w * 16 + ml) * HD + qd * 8;
    aq[0] = *(const short8*)qr;
    aq[1] = *(const short8*)(qr + 32);
  }

  const int srow = tid >> 2;                       // staging row (key or d)
  const int jg = (tid & 3) ^ ((tid >> 3) & 3);     // swizzled 16B chunk

  // prologue: tile 0 -> buf 0
#pragma unroll
  for (int s = 0; s < 2; ++s) {
    gload16(&Ks[s * 2048 + tid * 8], Kb + (size_t)srow * HD + s * 32 + jg * 8);
    gload16(&Vs[s * 2048 + tid * 8], Vb + (size_t)srow * NS + s * 32 + jg * 8);
  }
  __syncthreads();

  f32x4 O[4];
#pragma unroll
  for (int i = 0; i < 4; ++i) O[i] = (f32x4){0.f, 0.f, 0.f, 0.f};
  f32x4 lsum4 = (f32x4){0.f, 0.f, 0.f, 0.f};  // packed row-sum accumulator

  for (int kb = 0; kb < NS / 64; ++kb) {
    const int cur = kb & 1, nxt = cur ^ 1;
    if (kb < NS / 64 - 1) {  // prefetch tile kb+1 into the other buffer
#pragma unroll
      for (int s = 0; s < 2; ++s) {
        gload16(&Ks[(nxt * 2 + s) * 2048 + tid * 8],
                Kb + (size_t)((kb + 1) * 64 + srow) * HD + s * 32 + jg * 8);
        gload16(&Vs[(nxt * 2 + s) * 2048 + tid * 8],
                Vb + (size_t)srow * NS + (kb + 1) * 64 + s * 32 + jg * 8);
      }
    }

    // S^T = K Q^T  (D[key][qrow]; A=K frag, B=Q frag)
    const u16* kbase = &Ks[cur * 2 * 2048];
    f32x4 S[4];
#pragma unroll
    for (int f = 0; f < 4; ++f) S[f] = (f32x4){0.f, 0.f, 0.f, 0.f};
#pragma unroll
    for (int f = 0; f < 4; ++f)
#pragma unroll
      for (int ks = 0; ks < 2; ++ks) {
        short8 bk = *(const short8*)&kbase[ks * 2048 + (f * 16 + ml) * 32 +
                                           ((qd ^ sml) * 8)];
        S[f] = __builtin_amdgcn_mfma_f32_16x16x32_bf16(bk, aq[ks], S[f], 0, 0, 0);
      }

    // P = exp2(S^T) in registers; packed cvt to MFMA frags
    s16x4 pf[4];
#pragma unroll
    for (int f = 0; f < 4; ++f) {
      f32x4 p;
      p.x = __builtin_amdgcn_exp2f(S[f][0]);
      p.y = __builtin_amdgcn_exp2f(S[f][1]);
      p.z = __builtin_amdgcn_exp2f(S[f][2]);
      p.w = __builtin_amdgcn_exp2f(S[f][3]);
      lsum4 += p;
      pf[f] = pkbf4s(p.x, p.y, p.z, p.w);
    }

    // O^T += V P  (A=V frag, B=P frag; 16 keys per step)
    const u16* vbase = &Vs[cur * 2 * 2048];
#pragma unroll
    for (int t = 0; t < 4; ++t) {
      const int vs = t >> 1;
      const int voff = ((((t & 1) * 2 + (qd >> 1)) ^ sml) * 8) + (qd & 1) * 4;
#pragma unroll
      for (int df = 0; df < 4; ++df) {
        s16x4 vb = *(const s16x4*)&vbase[vs * 2048 + (df * 16 + ml) * 32 + voff];
        O[df] = MFMA_PV(vb, pf[t], O[df]);
      }
    }
    __syncthreads();  // readers of cur done + prefetch into nxt drained
  }

  // lsum holds partial sums for qrow=ml over this quad's keys; reduce over quads
  float lsum = (lsum4.x + lsum4.y) + (lsum4.z + lsum4.w);
  lsum += __shfl_xor(lsum, 16);
  lsum += __shfl_xor(lsum, 32);
  const float linv = 1.f / lsum;  // qrow = ml (O^T col)

  // O^T: lane holds O[d = df*16 + qd*4 + reg][qrow = ml] -> [b][n][h*64+d]
  u16* xb = XO + ((size_t)(b * NS) + n0 + w * 16 + ml) * DM + h * 64;
#pragma unroll
  for (int df = 0; df < 4; ++df) {
    *(u16x4*)(xb + df * 16 + qd * 4) =
        pkbf4(O[df][0] * linv, O[df][1] * linv, O[df][2] * linv, O[df][3] * linv);
  }
}

extern "C" void kernel_launch(void* const* d_in, const int* in_sizes, int n_in,
                              void* d_out, int out_size, void* d_ws, size_t ws_size,
                              hipStream_t stream) {
  const float* query = (const float*)d_in[0];
  const float* key = (const float*)d_in[1];
  const float* value = (const float*)d_in[2];
  const float* Wq = (const float*)d_in[3]; const float* bq = (const float*)d_in[4];
  const float* Wk = (const float*)d_in[5]; const float* bk = (const float*)d_in[6];
  const float* Wv = (const float*)d_in[7]; const float* bv = (const float*)d_in[8];
  const float* Wm = (const float*)d_in[9]; const float* bm = (const float*)d_in[10];

  u16* ws = (u16*)d_ws;
  const size_t TS = (size_t)2 * NS * DM;   // 4,194,304 u16 elems
  const size_t WSZ = (size_t)DM * DM;
  u16* XTq = ws;
  u16* XTk = ws + TS;
  u16* XTv = ws + 2 * TS;
  u16* QH = ws + 3 * TS;
  u16* KH = ws + 4 * TS;
  u16* VH = ws + 5 * TS;
  u16* Wqb = ws + 6 * TS;
  u16* Wkb = Wqb + WSZ;
  u16* Wvb = Wkb + WSZ;
  u16* Wmb = Wvb + WSZ;  // Wm with permuted columns (j = h*64+d)
  u16* XO = XTq;   // attn out [b][n][h*64+d]; XTq fully consumed by qkv_k

  cvt3_k<<<dim3(WSZ / 1024, 3), 256, 0, stream>>>(Wq, Wk, Wv, Wqb, Wkb, Wvb);
  cvtp_k<<<DM / 4, 256, 0, stream>>>(Wm, Wmb);

  dim3 tb(16, 16);
  trf3_k<<<dim3(NS / 64, DM / 64, 6), tb, 0, stream>>>(query, key, value, XTq, XTk, XTv);

  qkv_k<<<dim3(NS / 128, DM / 128, 6), 256, 0, stream>>>(
      XTq, XTk, XTv, Wqb, Wkb, Wvb, bq, bk, bv, QH, KH, VH);

  attn_k<<<dim3(NS / 64, 32), 256, 0, stream>>>(QH, KH, VH, XO);

  proj_o<<<dim3(NS / 64, DM / 128, 2), 256, 0, stream>>>(XO, Wmb, bm, (float*)d_out);
}